// Round 7
// baseline (12.732 us; speedup 1.0000x reference)
//
#include <hip/hip_runtime.h>
#include <math.h>

// Fused SPDS extractor, single dispatch (R6):
//   for p in {2,4,8}: sliding p×p patches (stride p/2) -> per-patch mean,
//   std(ddof=1)+1e-6, and (p==2) channel-mean of sign(det)*|det|^0.7,
//   each plane bilinear-resized (align_corners=False) to 32x32.
//
// R6: P=8 goes SEPARABLE via LDS. A P=8 patch is exactly 2x2 blocks of 4x4
// (row/col starts are 4-aligned), so per (b, c, 8-output-row band):
//   pass A : stream the band's 68 input rows once (coalesced float4) ->
//            2x2 block {sum, sumsq} grid in LDS (34 x 128 cells)
//   pass A5: 4x4 block grid (17 x 64 cells) by summing 2x2 cells
//   pass B : each (pixel, y-corner) reads 2x3 B44 cells; left patch =
//            cols {0,1}, right = {1,2}; blend x locally, shfl_xor(1) y-add.
// Bands (verified exact, never clamp): R0 = {0,64,124,188}, 68 rows each.
// Global loads for P=8: 3.5M -> 1.67M instrs (56 -> 27 MB, ~compulsory),
// streamed first-touch warms L2/L3 for the P=4/P=2 gather blocks after.
// P=4 / P=2 keep the R4 structure (x-union + select-free y-split).

__device__ __forceinline__ float hsum4(float4 q) { return q.x + q.y + q.z + q.w; }
__device__ __forceinline__ float hsq4(float4 q) {
    return q.x * q.x + q.y * q.y + q.z * q.z + q.w * q.w;
}

// sign(x)*|x|^0.7 via hardware exp2/log2 (abs threshold 5.7e-2 >> error)
__device__ __forceinline__ float signed_pow07(float raw) {
    float a = fabsf(raw);
    float r = exp2f(0.7f * log2f(fmaxf(a, 1e-38f)));   // a==0 -> ~3e-27 ~ 0
    return copysignf(r, raw);
}

// bilinear coord helper, align_corners=False
template <int N>
__device__ __forceinline__ void bilin(int o, int& lo, float& w) {
    const float scale = (float)N / 32.0f;
    float s = (o + 0.5f) * scale - 0.5f;
    s = fminf(fmaxf(s, 0.0f), (float)(N - 1));
    lo = (int)floorf(s);
    w = s - (float)lo;
}

// ---- P=4 and P=2 (R4 structure): thread = (b, oy, ox, lane_y) ----
template <int P, int CHBASE>
__device__ __forceinline__ void spds_scale(const float* __restrict__ x,
                                           float* __restrict__ out, int tid) {
    constexpr int N = (256 - P) / (P / 2) + 1;   // 127 / 255
    constexpr int NV = (P == 2) ? 7 : 6;
    constexpr int PP = P * P;
    constexpr float INV_PP   = 1.0f / PP;
    constexpr float INV_PPM1 = 1.0f / (PP - 1);

    int lane_y = tid & 1;
    int t      = tid >> 1;
    int ox     = t & 31;
    int oy     = (t >> 5) & 31;
    int b      = t >> 10;

    int yl, xl; float wy, wx;
    bilin<N>(oy, yl, wy);
    bilin<N>(ox, xl, wx);

    float wly = lane_y ? wy : (1.0f - wy);
    float wl  = (1.0f - wx) * wly;
    float wr  = wx * wly;

    const float* xb = x + (size_t)b * 3 * 65536 + xl * (P / 2);

    float vals[7];
    float det = 0.0f;

    #pragma unroll
    for (int c = 0; c < 3; ++c) {
        const float* xc = xb + (size_t)c * 65536;
        float sl, ssl, sr, ssr;
        float rawl = 0.0f, rawr = 0.0f;

        if constexpr (P == 4) {
            // row union [2yl, 2yl+6): lane0 rows +0..2 fwd, lane1 +5..3 rev
            int rb    = yl * 2 + (lane_y ? 5 : 0);
            int rstep = lane_y ? -256 : 256;
            const float* p = xc + rb * 256;
            float Xs_l = 0, Xs_r = 0, Xq_l = 0, Xq_r = 0;
            float Ys_l = 0, Ys_r = 0, Yq_l = 0, Yq_r = 0;
            #pragma unroll
            for (int dy = 0; dy < 3; ++dy) {
                const float2* r = reinterpret_cast<const float2*>(p);
                float2 u = r[0], v = r[1], w2 = r[2];
                float s0 = u.x + u.y, s1 = v.x + v.y, s2 = w2.x + w2.y;
                float t0 = u.x * u.x + u.y * u.y;
                float t1 = v.x * v.x + v.y * v.y;
                float t2 = w2.x * w2.x + w2.y * w2.y;
                float srl = s0 + s1, srr = s1 + s2;
                float trl = t0 + t1, trr = t1 + t2;
                Xs_l += srl; Xs_r += srr; Xq_l += trl; Xq_r += trr;
                if (dy < 2) { Ys_l += srl; Ys_r += srr; Yq_l += trl; Yq_r += trr; }
                p += rstep;
            }
            float Zs_l = Xs_l - Ys_l, Zs_r = Xs_r - Ys_r;
            float Zq_l = Xq_l - Yq_l, Zq_r = Xq_r - Yq_r;
            sl  = Xs_l + __shfl_xor(Zs_l, 1);
            sr  = Xs_r + __shfl_xor(Zs_r, 1);
            ssl = Xq_l + __shfl_xor(Zq_l, 1);
            ssr = Xq_r + __shfl_xor(Zq_r, 1);
        } else {  // P == 2: 2 rows x 3 cols in-lane; both 2x2 dets need raws
            const float* p0 = xc + (yl + lane_y) * 256;
            float a  = p0[0],   b2 = p0[1],   e = p0[2];
            float c2 = p0[256], d  = p0[257], g = p0[258];
            sl  = a + b2 + c2 + d;
            sr  = b2 + e + d + g;
            ssl = a * a + b2 * b2 + c2 * c2 + d * d;
            ssr = b2 * b2 + e * e + d * d + g * g;
            rawl = a * d - b2 * c2;
            rawr = b2 * g - e * d;
        }

        float ml = sl * INV_PP, mr = sr * INV_PP;
        float vl = (ssl - sl * sl * INV_PP) * INV_PPM1;
        float vr = (ssr - sr * sr * INV_PP) * INV_PPM1;
        float dl = sqrtf(fmaxf(vl, 0.0f)) + 1e-6f;
        float dr = sqrtf(fmaxf(vr, 0.0f)) + 1e-6f;

        vals[c]     = ml * wl + mr * wr;
        vals[3 + c] = dl * wl + dr * wr;
        if constexpr (P == 2)
            det += signed_pow07(rawl) * wl + signed_pow07(rawr) * wr;
    }
    if constexpr (P == 2) vals[6] = det * (1.0f / 3.0f);

    #pragma unroll
    for (int i = 0; i < NV; ++i) {
        float v = vals[i];
        v += __shfl_xor(v, 1);
        vals[i] = v;
    }

    if (lane_y == 0) {
        float* ob = out + ((size_t)b * 19 + CHBASE) * 1024 + oy * 32 + ox;
        #pragma unroll
        for (int i = 0; i < NV; ++i)
            ob[(size_t)i * 1024] = vals[i];
    }
}

__global__ __launch_bounds__(256) void spds_fused(const float* __restrict__ x,
                                                  float* __restrict__ out,
                                                  int nb8, int bps) {
    // LDS: 2x2 block cells {s,ss} 34x128, then 4x4 cells 17x64 (43.5 KB)
    __shared__ float2 B22[34 * 128];
    __shared__ float2 B44[17 * 64];

    int bid = blockIdx.x;
    if (bid < nb8) {
        // ---- P=8 separable: block = (b, c, band t) ----
        int rem = bid % 12;
        int b   = bid / 12;
        int c   = rem >> 2;
        int t   = rem & 3;
        const int R0q_tab[4] = {0, 16, 31, 47};     // band start in r4 units
        int R0q = R0q_tab[t];
        int R0  = R0q * 4;                          // first input row (4-aligned)

        const float* xc = x + ((size_t)b * 3 + c) * 65536;

        // pass A: 34 r2-rows x 64 quads = 2176 tasks; 2 float4 loads each
        #pragma unroll
        for (int k = 0; k < 9; ++k) {
            int tau = threadIdx.x + 256 * k;
            if (tau < 34 * 64) {
                int q = tau & 63;                   // quad (4 cols at 4q)
                int r2 = tau >> 6;
                const float* p = xc + (R0 + 2 * r2) * 256 + 4 * q;
                float4 a  = *reinterpret_cast<const float4*>(p);
                float4 b4 = *reinterpret_cast<const float4*>(p + 256);
                float s0  = a.x + a.y + b4.x + b4.y;
                float ss0 = a.x * a.x + a.y * a.y + b4.x * b4.x + b4.y * b4.y;
                float s1  = a.z + a.w + b4.z + b4.w;
                float ss1 = a.z * a.z + a.w * a.w + b4.z * b4.z + b4.w * b4.w;
                B22[2 * tau]     = make_float2(s0, ss0);   // (r2, c2=2q)
                B22[2 * tau + 1] = make_float2(s1, ss1);   // (r2, c2=2q+1)
            }
        }
        __syncthreads();

        // pass A5: 17 x 64 = 1088 tasks -> B44
        #pragma unroll
        for (int k = 0; k < 5; ++k) {
            int tau = threadIdx.x + 256 * k;
            if (tau < 17 * 64) {
                int c4 = tau & 63;
                int r4 = tau >> 6;
                int i0 = (2 * r4) * 128 + 2 * c4;
                float2 p00 = B22[i0],       p01 = B22[i0 + 1];
                float2 p10 = B22[i0 + 128], p11 = B22[i0 + 129];
                B44[tau] = make_float2(p00.x + p01.x + p10.x + p11.x,
                                       p00.y + p01.y + p10.y + p11.y);
            }
        }
        __syncthreads();

        // pass B: 8 oy x 32 ox x 2 y-corners = 512 tasks
        constexpr float INV_PP = 1.0f / 64.0f, INV_PPM1 = 1.0f / 63.0f;
        #pragma unroll
        for (int k = 0; k < 2; ++k) {
            int tau = threadIdx.x + 256 * k;
            int ly  = tau & 1;
            int pix = tau >> 1;
            int ox  = pix & 31;
            int oy  = t * 8 + (pix >> 5);

            int yl, xl; float wy, wx;
            bilin<63>(oy, yl, wy);
            bilin<63>(ox, xl, wx);

            float wly = ly ? wy : (1.0f - wy);
            float wl  = (1.0f - wx) * wly;
            float wr  = wx * wly;

            int rr = yl + ly - R0q;                 // in [0,15]
            const float2* r0 = &B44[rr * 64 + xl];
            const float2* r1 = r0 + 64;
            float2 c00 = r0[0], c01 = r0[1], c02 = r0[2];
            float2 c10 = r1[0], c11 = r1[1], c12 = r1[2];

            float sl  = c00.x + c01.x + c10.x + c11.x;
            float ssl = c00.y + c01.y + c10.y + c11.y;
            float sr  = c01.x + c02.x + c11.x + c12.x;
            float ssr = c01.y + c02.y + c11.y + c12.y;

            float ml = sl * INV_PP, mr = sr * INV_PP;
            float vlv = (ssl - sl * sl * INV_PP) * INV_PPM1;
            float vrv = (ssr - sr * sr * INV_PP) * INV_PPM1;
            float dl = sqrtf(fmaxf(vlv, 0.0f)) + 1e-6f;
            float dr = sqrtf(fmaxf(vrv, 0.0f)) + 1e-6f;

            float vmean = ml * wl + mr * wr;
            float vstd  = dl * wl + dr * wr;
            vmean += __shfl_xor(vmean, 1);
            vstd  += __shfl_xor(vstd, 1);

            if (ly == 0) {
                float* ob = out + ((size_t)b * 19 + 13 + c) * 1024 + oy * 32 + ox;
                ob[0]        = vmean;   // ch 13+c
                ob[3 * 1024] = vstd;    // ch 16+c
            }
        }
    } else if (bid < nb8 + bps) {
        spds_scale<4, 7>(x, out, (bid - nb8) * 256 + threadIdx.x);
    } else {
        spds_scale<2, 0>(x, out, (bid - nb8 - bps) * 256 + threadIdx.x);
    }
}

extern "C" void kernel_launch(void* const* d_in, const int* in_sizes, int n_in,
                              void* d_out, int out_size, void* d_ws, size_t ws_size,
                              hipStream_t stream) {
    const float* x   = (const float*)d_in[0];
    float*       out = (float*)d_out;
    int B = in_sizes[0] / (3 * 256 * 256);  // 32
    int nb8 = B * 12;                       // (b, c, 4 bands)
    int bps = B * 8;                        // B*1024px*2 lanes / 256
    spds_fused<<<nb8 + 2 * bps, 256, 0, stream>>>(x, out, nb8, bps);
}

// Round 8
// 12.408 us; speedup vs baseline: 1.0261x; 1.0261x over previous
//
#include <hip/hip_runtime.h>
#include <math.h>

// Fused SPDS extractor, single dispatch (R7):
//   for p in {2,4,8}: sliding p×p patches (stride p/2) -> per-patch mean,
//   std(ddof=1)+1e-6, and (p==2) channel-mean of sign(det)*|det|^0.7,
//   each plane bilinear-resized (align_corners=False) to 32x32.
//
// R7: P=8 separable via a SMALL LDS footprint. A P=8 patch = 2x2 blocks of
// 4x4 (starts are 4-aligned). Per (b, c, 8-output-row band):
//   pass A: each task loads one 4x4 block (4 coalesced float4 rows) and
//           writes its {sum, sumsq} to B44 (17 x 64 float2 = 8.7 KB LDS —
//           R6's 43.5 KB B22 intermediate deleted; it capped the WHOLE
//           grid at 3 blocks/CU since static LDS is per-kernel).
//   pass B: each (pixel, y-corner) reads 2x3 B44 cells; left patch =
//           cols {0,1}, right = {1,2}; blend x locally, shfl_xor(1) y-add.
// Bands (verified exact, never clamp): R0 = {0,64,124,188}, 68 rows each.
// P=8 global loads: 3.5M -> 1.67M instrs (56 -> 27 MB ~ compulsory).
// P=4 / P=2 keep the R4 gather structure (x-union + select-free y-split).

__device__ __forceinline__ float hsum4(float4 q) { return q.x + q.y + q.z + q.w; }
__device__ __forceinline__ float hsq4(float4 q) {
    return q.x * q.x + q.y * q.y + q.z * q.z + q.w * q.w;
}

// sign(x)*|x|^0.7 via hardware exp2/log2 (abs threshold 5.7e-2 >> error)
__device__ __forceinline__ float signed_pow07(float raw) {
    float a = fabsf(raw);
    float r = exp2f(0.7f * log2f(fmaxf(a, 1e-38f)));   // a==0 -> ~3e-27 ~ 0
    return copysignf(r, raw);
}

// bilinear coord helper, align_corners=False
template <int N>
__device__ __forceinline__ void bilin(int o, int& lo, float& w) {
    const float scale = (float)N / 32.0f;
    float s = (o + 0.5f) * scale - 0.5f;
    s = fminf(fmaxf(s, 0.0f), (float)(N - 1));
    lo = (int)floorf(s);
    w = s - (float)lo;
}

// ---- P=4 and P=2 (R4 structure): thread = (b, oy, ox, lane_y) ----
template <int P, int CHBASE>
__device__ __forceinline__ void spds_scale(const float* __restrict__ x,
                                           float* __restrict__ out, int tid) {
    constexpr int N = (256 - P) / (P / 2) + 1;   // 127 / 255
    constexpr int NV = (P == 2) ? 7 : 6;
    constexpr int PP = P * P;
    constexpr float INV_PP   = 1.0f / PP;
    constexpr float INV_PPM1 = 1.0f / (PP - 1);

    int lane_y = tid & 1;
    int t      = tid >> 1;
    int ox     = t & 31;
    int oy     = (t >> 5) & 31;
    int b      = t >> 10;

    int yl, xl; float wy, wx;
    bilin<N>(oy, yl, wy);
    bilin<N>(ox, xl, wx);

    float wly = lane_y ? wy : (1.0f - wy);
    float wl  = (1.0f - wx) * wly;
    float wr  = wx * wly;

    const float* xb = x + (size_t)b * 3 * 65536 + xl * (P / 2);

    float vals[7];
    float det = 0.0f;

    #pragma unroll
    for (int c = 0; c < 3; ++c) {
        const float* xc = xb + (size_t)c * 65536;
        float sl, ssl, sr, ssr;
        float rawl = 0.0f, rawr = 0.0f;

        if constexpr (P == 4) {
            // row union [2yl, 2yl+6): lane0 rows +0..2 fwd, lane1 +5..3 rev
            int rb    = yl * 2 + (lane_y ? 5 : 0);
            int rstep = lane_y ? -256 : 256;
            const float* p = xc + rb * 256;
            float Xs_l = 0, Xs_r = 0, Xq_l = 0, Xq_r = 0;
            float Ys_l = 0, Ys_r = 0, Yq_l = 0, Yq_r = 0;
            #pragma unroll
            for (int dy = 0; dy < 3; ++dy) {
                const float2* r = reinterpret_cast<const float2*>(p);
                float2 u = r[0], v = r[1], w2 = r[2];
                float s0 = u.x + u.y, s1 = v.x + v.y, s2 = w2.x + w2.y;
                float t0 = u.x * u.x + u.y * u.y;
                float t1 = v.x * v.x + v.y * v.y;
                float t2 = w2.x * w2.x + w2.y * w2.y;
                float srl = s0 + s1, srr = s1 + s2;
                float trl = t0 + t1, trr = t1 + t2;
                Xs_l += srl; Xs_r += srr; Xq_l += trl; Xq_r += trr;
                if (dy < 2) { Ys_l += srl; Ys_r += srr; Yq_l += trl; Yq_r += trr; }
                p += rstep;
            }
            float Zs_l = Xs_l - Ys_l, Zs_r = Xs_r - Ys_r;
            float Zq_l = Xq_l - Yq_l, Zq_r = Xq_r - Yq_r;
            sl  = Xs_l + __shfl_xor(Zs_l, 1);
            sr  = Xs_r + __shfl_xor(Zs_r, 1);
            ssl = Xq_l + __shfl_xor(Zq_l, 1);
            ssr = Xq_r + __shfl_xor(Zq_r, 1);
        } else {  // P == 2: 2 rows x 3 cols in-lane; both 2x2 dets need raws
            const float* p0 = xc + (yl + lane_y) * 256;
            float a  = p0[0],   b2 = p0[1],   e = p0[2];
            float c2 = p0[256], d  = p0[257], g = p0[258];
            sl  = a + b2 + c2 + d;
            sr  = b2 + e + d + g;
            ssl = a * a + b2 * b2 + c2 * c2 + d * d;
            ssr = b2 * b2 + e * e + d * d + g * g;
            rawl = a * d - b2 * c2;
            rawr = b2 * g - e * d;
        }

        float ml = sl * INV_PP, mr = sr * INV_PP;
        float vl = (ssl - sl * sl * INV_PP) * INV_PPM1;
        float vr = (ssr - sr * sr * INV_PP) * INV_PPM1;
        float dl = sqrtf(fmaxf(vl, 0.0f)) + 1e-6f;
        float dr = sqrtf(fmaxf(vr, 0.0f)) + 1e-6f;

        vals[c]     = ml * wl + mr * wr;
        vals[3 + c] = dl * wl + dr * wr;
        if constexpr (P == 2)
            det += signed_pow07(rawl) * wl + signed_pow07(rawr) * wr;
    }
    if constexpr (P == 2) vals[6] = det * (1.0f / 3.0f);

    #pragma unroll
    for (int i = 0; i < NV; ++i) {
        float v = vals[i];
        v += __shfl_xor(v, 1);
        vals[i] = v;
    }

    if (lane_y == 0) {
        float* ob = out + ((size_t)b * 19 + CHBASE) * 1024 + oy * 32 + ox;
        #pragma unroll
        for (int i = 0; i < NV; ++i)
            ob[(size_t)i * 1024] = vals[i];
    }
}

__global__ __launch_bounds__(256) void spds_fused(const float* __restrict__ x,
                                                  float* __restrict__ out,
                                                  int nb8, int bps) {
    // 4x4 block {sum,sumsq} grid: 17 rows x 64 cols, 8.7 KB (all blocks pay
    // this — small enough that wave count, not LDS, limits occupancy)
    __shared__ float2 B44[17 * 64];

    int bid = blockIdx.x;
    if (bid < nb8) {
        // ---- P=8 separable: block = (b, c, band t) ----
        int rem = bid % 12;
        int b   = bid / 12;
        int c   = rem >> 2;
        int t   = rem & 3;
        const int R0q_tab[4] = {0, 16, 31, 47};     // band start in r4 units
        int R0q = R0q_tab[t];
        int R0  = R0q * 4;                          // first input row (4-aligned)

        const float* xc = x + ((size_t)b * 3 + c) * 65536;

        // pass A: 17 r4-rows x 64 quads = 1088 tasks; 4 coalesced float4 each
        #pragma unroll
        for (int k = 0; k < 5; ++k) {
            int tau = threadIdx.x + 256 * k;
            if (tau < 17 * 64) {
                int c4 = tau & 63;
                int r4 = tau >> 6;
                const float* p = xc + (R0 + 4 * r4) * 256 + 4 * c4;
                float4 a0 = *reinterpret_cast<const float4*>(p);
                float4 a1 = *reinterpret_cast<const float4*>(p + 256);
                float4 a2 = *reinterpret_cast<const float4*>(p + 512);
                float4 a3 = *reinterpret_cast<const float4*>(p + 768);
                float s  = hsum4(a0) + hsum4(a1) + hsum4(a2) + hsum4(a3);
                float ss = hsq4(a0) + hsq4(a1) + hsq4(a2) + hsq4(a3);
                B44[tau] = make_float2(s, ss);
            }
        }
        __syncthreads();

        // pass B: 8 oy x 32 ox x 2 y-corners = 512 tasks
        constexpr float INV_PP = 1.0f / 64.0f, INV_PPM1 = 1.0f / 63.0f;
        #pragma unroll
        for (int k = 0; k < 2; ++k) {
            int tau = threadIdx.x + 256 * k;
            int ly  = tau & 1;
            int pix = tau >> 1;
            int ox  = pix & 31;
            int oy  = t * 8 + (pix >> 5);

            int yl, xl; float wy, wx;
            bilin<63>(oy, yl, wy);
            bilin<63>(ox, xl, wx);

            float wly = ly ? wy : (1.0f - wy);
            float wl  = (1.0f - wx) * wly;
            float wr  = wx * wly;

            int rr = yl + ly - R0q;                 // in [0,16)
            const float2* r0 = &B44[rr * 64 + xl];
            const float2* r1 = r0 + 64;
            float2 c00 = r0[0], c01 = r0[1], c02 = r0[2];
            float2 c10 = r1[0], c11 = r1[1], c12 = r1[2];

            float sl  = c00.x + c01.x + c10.x + c11.x;
            float ssl = c00.y + c01.y + c10.y + c11.y;
            float sr  = c01.x + c02.x + c11.x + c12.x;
            float ssr = c01.y + c02.y + c11.y + c12.y;

            float ml = sl * INV_PP, mr = sr * INV_PP;
            float vlv = (ssl - sl * sl * INV_PP) * INV_PPM1;
            float vrv = (ssr - sr * sr * INV_PP) * INV_PPM1;
            float dl = sqrtf(fmaxf(vlv, 0.0f)) + 1e-6f;
            float dr = sqrtf(fmaxf(vrv, 0.0f)) + 1e-6f;

            float vmean = ml * wl + mr * wr;
            float vstd  = dl * wl + dr * wr;
            vmean += __shfl_xor(vmean, 1);
            vstd  += __shfl_xor(vstd, 1);

            if (ly == 0) {
                float* ob = out + ((size_t)b * 19 + 13 + c) * 1024 + oy * 32 + ox;
                ob[0]        = vmean;   // ch 13+c
                ob[3 * 1024] = vstd;    // ch 16+c
            }
        }
    } else if (bid < nb8 + bps) {
        spds_scale<4, 7>(x, out, (bid - nb8) * 256 + threadIdx.x);
    } else {
        spds_scale<2, 0>(x, out, (bid - nb8 - bps) * 256 + threadIdx.x);
    }
}

extern "C" void kernel_launch(void* const* d_in, const int* in_sizes, int n_in,
                              void* d_out, int out_size, void* d_ws, size_t ws_size,
                              hipStream_t stream) {
    const float* x   = (const float*)d_in[0];
    float*       out = (float*)d_out;
    int B = in_sizes[0] / (3 * 256 * 256);  // 32
    int nb8 = B * 12;                       // (b, c, 4 bands)
    int bps = B * 8;                        // B*1024px*2 lanes / 256
    spds_fused<<<nb8 + 2 * bps, 256, 0, stream>>>(x, out, nb8, bps);
}

// Round 9
// 11.115 us; speedup vs baseline: 1.1455x; 1.1164x over previous
//
#include <hip/hip_runtime.h>
#include <math.h>

// Fused SPDS extractor, single dispatch (R8 = revert to R5, the best):
//   for p in {2,4,8}: sliding p×p patches (stride p/2) -> per-patch mean,
//   std(ddof=1)+1e-6, and (p==2) channel-mean of sign(det)*|det|^0.7,
//   each plane bilinear-resized (align_corners=False) to 32x32.
//
// Structure: 2 threads per output pixel (the two y-corners).
//  * x-union (R3): each lane loads the column union of the two x-corner
//    patches once per row; left = q0+q1, right = q1+q2 — both complete
//    in-lane, blended with x-weights locally, one shfl_xor(1) y-add.
//  * y-split (R4, select-free): lane pair splits the row union evenly;
//    odd lane iterates reversed so X (all rows) and Y (first iters) are
//    statically accumulated; top = X0+(X1-Y1), bot = X1+(X0-Y0) via one
//    shfl_xor(1) on Z=X-Y. No cndmask selects.
//  * channel-split P=8 (R5): one thread per (pixel, y-corner, CHANNEL).
// Measured dead ends (do not retry): R2 cross-lane select exchange (-15%),
// R6/R7 separable P=8 via LDS (-10% both at 43.5KB and 8.7KB LDS — the
// barrier kills per-thread load/compute overlap vs the plain gather).

__device__ __forceinline__ float hsum4(float4 q) { return q.x + q.y + q.z + q.w; }
__device__ __forceinline__ float hsq4(float4 q) {
    return q.x * q.x + q.y * q.y + q.z * q.z + q.w * q.w;
}

// sign(x)*|x|^0.7 via hardware exp2/log2 (abs threshold 5.7e-2 >> error)
__device__ __forceinline__ float signed_pow07(float raw) {
    float a = fabsf(raw);
    float r = exp2f(0.7f * log2f(fmaxf(a, 1e-38f)));   // a==0 -> ~3e-27 ~ 0
    return copysignf(r, raw);
}

// shared bilinear coord helper, align_corners=False
template <int N>
__device__ __forceinline__ void bilin(int o, int& lo, float& w) {
    const float scale = (float)N / 32.0f;
    float s = (o + 0.5f) * scale - 0.5f;
    s = fminf(fmaxf(s, 0.0f), (float)(N - 1));
    lo = (int)floorf(s);
    w = s - (float)lo;
}

// ---- P=8, channel-split: thread = (b, c, oy, ox, lane_y) ----
__device__ __forceinline__ void spds_scale8(const float* __restrict__ x,
                                            float* __restrict__ out, int tid) {
    constexpr int N = 63;
    constexpr float INV_PP = 1.0f / 64.0f, INV_PPM1 = 1.0f / 63.0f;

    int lane_y = tid & 1;
    int t      = tid >> 1;
    int ox     = t & 31;
    int oy     = (t >> 5) & 31;
    int u      = t >> 10;        // 0..3B-1 : (b, c)
    int b      = u / 3;
    int c      = u - 3 * b;

    int yl, xl; float wy, wx;
    bilin<N>(oy, yl, wy);
    bilin<N>(ox, xl, wx);

    float wly = lane_y ? wy : (1.0f - wy);
    float wl  = (1.0f - wx) * wly;
    float wr  = wx * wly;

    const float* xc = x + ((size_t)b * 3 + c) * 65536 + xl * 4;

    // row union [4yl, 4yl+12): lane0 rows +0..5 fwd, lane1 +11..6 rev
    int rb    = yl * 4 + (lane_y ? 11 : 0);
    int rstep = lane_y ? -256 : 256;
    const float* p = xc + rb * 256;
    float Xs_l = 0, Xs_r = 0, Xq_l = 0, Xq_r = 0;
    float Ys_l = 0, Ys_r = 0, Yq_l = 0, Yq_r = 0;
    #pragma unroll
    for (int dy = 0; dy < 6; ++dy) {
        const float4* r = reinterpret_cast<const float4*>(p);
        float4 q0 = r[0], q1 = r[1], q2 = r[2];
        float s0 = hsum4(q0), s1 = hsum4(q1), s2 = hsum4(q2);
        float t0 = hsq4(q0),  t1 = hsq4(q1),  t2 = hsq4(q2);
        float srl = s0 + s1, srr = s1 + s2;
        float trl = t0 + t1, trr = t1 + t2;
        Xs_l += srl; Xs_r += srr; Xq_l += trl; Xq_r += trr;
        if (dy < 4) { Ys_l += srl; Ys_r += srr; Yq_l += trl; Yq_r += trr; }
        p += rstep;
    }
    float Zs_l = Xs_l - Ys_l, Zs_r = Xs_r - Ys_r;
    float Zq_l = Xq_l - Yq_l, Zq_r = Xq_r - Yq_r;
    float sl  = Xs_l + __shfl_xor(Zs_l, 1);
    float sr  = Xs_r + __shfl_xor(Zs_r, 1);
    float ssl = Xq_l + __shfl_xor(Zq_l, 1);
    float ssr = Xq_r + __shfl_xor(Zq_r, 1);

    float ml = sl * INV_PP, mr = sr * INV_PP;
    float vl = (ssl - sl * sl * INV_PP) * INV_PPM1;
    float vr = (ssr - sr * sr * INV_PP) * INV_PPM1;
    float dl = sqrtf(fmaxf(vl, 0.0f)) + 1e-6f;
    float dr = sqrtf(fmaxf(vr, 0.0f)) + 1e-6f;

    float vmean = ml * wl + mr * wr;
    float vstd  = dl * wl + dr * wr;
    vmean += __shfl_xor(vmean, 1);
    vstd  += __shfl_xor(vstd, 1);

    if (lane_y == 0) {
        float* ob = out + ((size_t)b * 19 + 13 + c) * 1024 + oy * 32 + ox;
        ob[0]        = vmean;   // ch 13+c
        ob[3 * 1024] = vstd;    // ch 16+c
    }
}

// ---- P=4 and P=2: thread = (b, oy, ox, lane_y), loops channels ----
template <int P, int CHBASE>
__device__ __forceinline__ void spds_scale(const float* __restrict__ x,
                                           float* __restrict__ out, int tid) {
    constexpr int N = (256 - P) / (P / 2) + 1;   // 127 / 255
    constexpr int NV = (P == 2) ? 7 : 6;
    constexpr int PP = P * P;
    constexpr float INV_PP   = 1.0f / PP;
    constexpr float INV_PPM1 = 1.0f / (PP - 1);

    int lane_y = tid & 1;
    int t      = tid >> 1;
    int ox     = t & 31;
    int oy     = (t >> 5) & 31;
    int b      = t >> 10;

    int yl, xl; float wy, wx;
    bilin<N>(oy, yl, wy);
    bilin<N>(ox, xl, wx);

    float wly = lane_y ? wy : (1.0f - wy);
    float wl  = (1.0f - wx) * wly;
    float wr  = wx * wly;

    const float* xb = x + (size_t)b * 3 * 65536 + xl * (P / 2);

    float vals[7];
    float det = 0.0f;

    #pragma unroll
    for (int c = 0; c < 3; ++c) {
        const float* xc = xb + (size_t)c * 65536;
        float sl, ssl, sr, ssr;
        float rawl = 0.0f, rawr = 0.0f;

        if constexpr (P == 4) {
            // row union [2yl, 2yl+6): lane0 rows +0..2 fwd, lane1 +5..3 rev
            int rb    = yl * 2 + (lane_y ? 5 : 0);
            int rstep = lane_y ? -256 : 256;
            const float* p = xc + rb * 256;
            float Xs_l = 0, Xs_r = 0, Xq_l = 0, Xq_r = 0;
            float Ys_l = 0, Ys_r = 0, Yq_l = 0, Yq_r = 0;
            #pragma unroll
            for (int dy = 0; dy < 3; ++dy) {
                const float2* r = reinterpret_cast<const float2*>(p);
                float2 u = r[0], v = r[1], w2 = r[2];
                float s0 = u.x + u.y, s1 = v.x + v.y, s2 = w2.x + w2.y;
                float t0 = u.x * u.x + u.y * u.y;
                float t1 = v.x * v.x + v.y * v.y;
                float t2 = w2.x * w2.x + w2.y * w2.y;
                float srl = s0 + s1, srr = s1 + s2;
                float trl = t0 + t1, trr = t1 + t2;
                Xs_l += srl; Xs_r += srr; Xq_l += trl; Xq_r += trr;
                if (dy < 2) { Ys_l += srl; Ys_r += srr; Yq_l += trl; Yq_r += trr; }
                p += rstep;
            }
            float Zs_l = Xs_l - Ys_l, Zs_r = Xs_r - Ys_r;
            float Zq_l = Xq_l - Yq_l, Zq_r = Xq_r - Yq_r;
            sl  = Xs_l + __shfl_xor(Zs_l, 1);
            sr  = Xs_r + __shfl_xor(Zs_r, 1);
            ssl = Xq_l + __shfl_xor(Zq_l, 1);
            ssr = Xq_r + __shfl_xor(Zq_r, 1);
        } else {  // P == 2: 2 rows x 3 cols in-lane; both 2x2 dets need raws
            const float* p0 = xc + (yl + lane_y) * 256;
            float a  = p0[0],   b2 = p0[1],   e = p0[2];
            float c2 = p0[256], d  = p0[257], g = p0[258];
            sl  = a + b2 + c2 + d;
            sr  = b2 + e + d + g;
            ssl = a * a + b2 * b2 + c2 * c2 + d * d;
            ssr = b2 * b2 + e * e + d * d + g * g;
            rawl = a * d - b2 * c2;
            rawr = b2 * g - e * d;
        }

        float ml = sl * INV_PP, mr = sr * INV_PP;
        float vl = (ssl - sl * sl * INV_PP) * INV_PPM1;
        float vr = (ssr - sr * sr * INV_PP) * INV_PPM1;
        float dl = sqrtf(fmaxf(vl, 0.0f)) + 1e-6f;
        float dr = sqrtf(fmaxf(vr, 0.0f)) + 1e-6f;

        vals[c]     = ml * wl + mr * wr;
        vals[3 + c] = dl * wl + dr * wr;
        if constexpr (P == 2)
            det += signed_pow07(rawl) * wl + signed_pow07(rawr) * wr;
    }
    if constexpr (P == 2) vals[6] = det * (1.0f / 3.0f);

    // add the two y-corners (lanes 2k, 2k+1)
    #pragma unroll
    for (int i = 0; i < NV; ++i) {
        float v = vals[i];
        v += __shfl_xor(v, 1);
        vals[i] = v;
    }

    if (lane_y == 0) {
        float* ob = out + ((size_t)b * 19 + CHBASE) * 1024 + oy * 32 + ox;
        #pragma unroll
        for (int i = 0; i < NV; ++i)
            ob[(size_t)i * 1024] = vals[i];
    }
}

__global__ __launch_bounds__(256) void spds_fused(const float* __restrict__ x,
                                                  float* __restrict__ out,
                                                  int bps8, int bps) {
    int bid = blockIdx.x;
    if (bid < bps8) {
        // heavy scale first, channel-split
        spds_scale8(x, out, bid * 256 + threadIdx.x);
    } else if (bid < bps8 + bps) {
        spds_scale<4, 7>(x, out, (bid - bps8) * 256 + threadIdx.x);
    } else {
        spds_scale<2, 0>(x, out, (bid - bps8 - bps) * 256 + threadIdx.x);
    }
}

extern "C" void kernel_launch(void* const* d_in, const int* in_sizes, int n_in,
                              void* d_out, int out_size, void* d_ws, size_t ws_size,
                              hipStream_t stream) {
    const float* x   = (const float*)d_in[0];
    float*       out = (float*)d_out;
    int B = in_sizes[0] / (3 * 256 * 256);  // 32
    int bps8 = B * 24;                      // B*3ch*1024px*2 lanes / 256
    int bps  = B * 8;                       // B*1024px*2 lanes / 256
    spds_fused<<<bps8 + 2 * bps, 256, 0, stream>>>(x, out, bps8, bps);
}